// Round 10
// baseline (386.985 us; speedup 1.0000x reference)
//
#include <hip/hip_runtime.h>

#define HH 64

// one-time: w2t[j*64+i] = w2[i*64+j]
static __global__ void k_prep_w2t(const float* __restrict__ w2, float* __restrict__ w2t){
  int t = blockIdx.x * 256 + threadIdx.x;   // 16 blocks x 256 = 4096
  w2t[t] = w2[(t & 63) * HH + (t >> 6)];
}

// ===================== pair-MLP core (LDS weights) ==========
// ~6.7k pts/us chip-wide, LDS-datapath-bound (8 ds_read_b128/wave-j).
__device__ __forceinline__ void mlp_pair(
    const float* __restrict__ sw1,   // LDS: x[64] y[64] z[64] b1[64]
    const float* __restrict__ sw2t,  // LDS: 4096
    const float* __restrict__ b2, const float* __restrict__ w3,
    const float* __restrict__ b3,
    float xA, float yA, float zA, float xB, float yB, float zB,
    float& outA, float& outB)
{
  const int ibase = ((threadIdx.x & 63) >> 5) * 32;
  float h1a[32], h1b[32];
  #pragma unroll
  for (int k = 0; k < 32; k += 4){
    const float4 wx = *(const float4*)&sw1[      ibase + k];
    const float4 wy = *(const float4*)&sw1[ 64 + ibase + k];
    const float4 wz = *(const float4*)&sw1[128 + ibase + k];
    const float4 bb = *(const float4*)&sw1[192 + ibase + k];
    h1a[k+0] = fmaxf(fmaf(xA,wx.x,fmaf(yA,wy.x,fmaf(zA,wz.x,bb.x))),0.f);
    h1a[k+1] = fmaxf(fmaf(xA,wx.y,fmaf(yA,wy.y,fmaf(zA,wz.y,bb.y))),0.f);
    h1a[k+2] = fmaxf(fmaf(xA,wx.z,fmaf(yA,wy.z,fmaf(zA,wz.z,bb.z))),0.f);
    h1a[k+3] = fmaxf(fmaf(xA,wx.w,fmaf(yA,wy.w,fmaf(zA,wz.w,bb.w))),0.f);
    h1b[k+0] = fmaxf(fmaf(xB,wx.x,fmaf(yB,wy.x,fmaf(zB,wz.x,bb.x))),0.f);
    h1b[k+1] = fmaxf(fmaf(xB,wx.y,fmaf(yB,wy.y,fmaf(zB,wz.y,bb.y))),0.f);
    h1b[k+2] = fmaxf(fmaf(xB,wx.z,fmaf(yB,wy.z,fmaf(zB,wz.z,bb.z))),0.f);
    h1b[k+3] = fmaxf(fmaf(xB,wx.w,fmaf(yB,wy.w,fmaf(zB,wz.w,bb.w))),0.f);
  }
  float oa = b3[0], ob = oa;
  #pragma unroll 1
  for (int j = 0; j < HH; ++j){
    const float4* wrow = (const float4*)&sw2t[j*HH + ibase];
    float a0 = 0.f, a1 = 0.f, c0 = 0.f, c1 = 0.f;
    #pragma unroll
    for (int q = 0; q < 8; q += 2){
      const float4 w0 = wrow[q];
      const float4 w1q = wrow[q+1];
      a0 = fmaf(h1a[4*q+0], w0.x, a0);
      a0 = fmaf(h1a[4*q+1], w0.y, a0);
      a0 = fmaf(h1a[4*q+2], w0.z, a0);
      a0 = fmaf(h1a[4*q+3], w0.w, a0);
      a1 = fmaf(h1a[4*q+4], w1q.x, a1);
      a1 = fmaf(h1a[4*q+5], w1q.y, a1);
      a1 = fmaf(h1a[4*q+6], w1q.z, a1);
      a1 = fmaf(h1a[4*q+7], w1q.w, a1);
      c0 = fmaf(h1b[4*q+0], w0.x, c0);
      c0 = fmaf(h1b[4*q+1], w0.y, c0);
      c0 = fmaf(h1b[4*q+2], w0.z, c0);
      c0 = fmaf(h1b[4*q+3], w0.w, c0);
      c1 = fmaf(h1b[4*q+4], w1q.x, c1);
      c1 = fmaf(h1b[4*q+5], w1q.y, c1);
      c1 = fmaf(h1b[4*q+6], w1q.z, c1);
      c1 = fmaf(h1b[4*q+7], w1q.w, c1);
    }
    float accA = a0 + a1, accB = c0 + c1;
    accA += __shfl_xor(accA, 32);
    accB += __shfl_xor(accB, 32);
    const float bj = b2[j], wj = w3[j];
    oa = fmaf(fmaxf(accA + bj, 0.f), wj, oa);
    ob = fmaf(fmaxf(accB + bj, 0.f), wj, ob);
  }
  outA = 1.f / (1.f + expf(-oa));
  outB = 1.f / (1.f + expf(-ob));
}

#define STAGE_WEIGHTS()                                            \
  __shared__ float sw1[4*HH];                                      \
  __shared__ float sw2t[HH*HH];                                    \
  {                                                                \
    const int t0 = threadIdx.x;                                    \
    if (t0 < 3*HH) sw1[t0] = w1[t0];                               \
    else sw1[t0] = b1[t0 - 3*HH];                                  \
    const float4* s4 = (const float4*)w2t;                         \
    float4* d4 = (float4*)sw2t;                                    \
    for (int i4 = t0; i4 < HH*HH/4; i4 += 256) d4[i4] = s4[i4];    \
    __syncthreads();                                               \
  }

// ---------------- dense pair eval (R=17, 33); optional calc=1 write ----------
static __global__ __launch_bounds__(256)
__attribute__((amdgpu_waves_per_eu(4,4)))
void k_eval_mlp(
    const float* __restrict__ w1, const float* __restrict__ b1,
    const float* __restrict__ w2t, const float* __restrict__ b2,
    const float* __restrict__ w3, const float* __restrict__ b3,
    float* __restrict__ out, unsigned char* __restrict__ calc1,
    int R, int s)
{
  STAGE_WEIGHTS();
  const unsigned int n = (unsigned int)R * (unsigned int)R * (unsigned int)R;
  const int lane = threadIdx.x & 63;
  const int wid = threadIdx.x >> 6;
  const unsigned int base = blockIdx.x * 256u + (unsigned int)(wid * 64 + (lane & 31));
  const unsigned int pidA = base < n ? base : (n - 1u);
  const unsigned int pB = base + 32u;
  const unsigned int pidB = pB < n ? pB : (n - 1u);
  const float inv129x2 = 2.0f / 129.0f;
  unsigned int cA = pidA % (unsigned int)R, rA = pidA / (unsigned int)R;
  unsigned int cB = pidB % (unsigned int)R, rB = pidB / (unsigned int)R;
  const float xA = ((float)(cA * (unsigned int)s) + 0.5f) * inv129x2 - 1.0f;
  const float yA = ((float)((rA % (unsigned int)R) * (unsigned int)s) + 0.5f) * inv129x2 - 1.0f;
  const float zA = ((float)((rA / (unsigned int)R) * (unsigned int)s) + 0.5f) * inv129x2 - 1.0f;
  const float xB = ((float)(cB * (unsigned int)s) + 0.5f) * inv129x2 - 1.0f;
  const float yB = ((float)((rB % (unsigned int)R) * (unsigned int)s) + 0.5f) * inv129x2 - 1.0f;
  const float zB = ((float)((rB / (unsigned int)R) * (unsigned int)s) + 0.5f) * inv129x2 - 1.0f;
  float oA, oB;
  mlp_pair(sw1, sw2t, b2, w3, b3, xA, yA, zA, xB, yB, zB, oA, oB);
  if ((threadIdx.x & 63) < 32){
    if (base < n){ out[pidA] = oA; if (calc1) calc1[pidA] = 1; }
    if (pB < n)  { out[pidB] = oB; if (calc1) calc1[pidB] = 1; }
  }
}

// ------------- sparse pair eval over compacted index list (R=65, 129) --------
static __global__ __launch_bounds__(256)
__attribute__((amdgpu_waves_per_eu(4,4)))
void k_eval_sparse(
    const float* __restrict__ w1, const float* __restrict__ b1,
    const float* __restrict__ w2t, const float* __restrict__ b2,
    const float* __restrict__ w3, const float* __restrict__ b3,
    const int* __restrict__ idxl, const unsigned int* __restrict__ cnt,
    const float* __restrict__ occ_i,
    float* __restrict__ out, unsigned char* __restrict__ mism,
    int R, int s, unsigned int n)
{
  unsigned int count = *cnt;
  if (count > n) count = n;               // guard vs stale ws during profiling replay
  if (blockIdx.x * 256u >= count) return;
  STAGE_WEIGHTS();
  const int lane = threadIdx.x & 63;
  const int wid = threadIdx.x >> 6;
  const unsigned int slotA = blockIdx.x * 256u + (unsigned int)(wid * 64 + (lane & 31));
  const unsigned int slotB = slotA + 32u;
  const bool vA = slotA < count, vB = slotB < count;
  const unsigned int pidA = (unsigned int)idxl[vA ? slotA : 0];
  const unsigned int pidB = (unsigned int)idxl[vB ? slotB : 0];
  const float inv129x2 = 2.0f / 129.0f;
  unsigned int cA = pidA % (unsigned int)R, rA = pidA / (unsigned int)R;
  unsigned int cB = pidB % (unsigned int)R, rB = pidB / (unsigned int)R;
  const float xA = ((float)(cA * (unsigned int)s) + 0.5f) * inv129x2 - 1.0f;
  const float yA = ((float)((rA % (unsigned int)R) * (unsigned int)s) + 0.5f) * inv129x2 - 1.0f;
  const float zA = ((float)((rA / (unsigned int)R) * (unsigned int)s) + 0.5f) * inv129x2 - 1.0f;
  const float xB = ((float)(cB * (unsigned int)s) + 0.5f) * inv129x2 - 1.0f;
  const float yB = ((float)((rB % (unsigned int)R) * (unsigned int)s) + 0.5f) * inv129x2 - 1.0f;
  const float zB = ((float)((rB / (unsigned int)R) * (unsigned int)s) + 0.5f) * inv129x2 - 1.0f;
  float oA, oB;
  mlp_pair(sw1, sw2t, b2, w3, b3, xA, yA, zA, xB, yB, zB, oA, oB);
  if ((threadIdx.x & 63) < 32){
    if (vA){
      out[pidA] = oA;
      mism[pidA] = ((occ_i[pidA] - 0.5f) * (oA - 0.5f) < 0.0f) ? (unsigned char)1 : (unsigned char)0;
    }
    if (vB){
      out[pidB] = oB;
      mism[pidB] = ((occ_i[pidB] - 0.5f) * (oB - 0.5f) < 0.0f) ? (unsigned char)1 : (unsigned char)0;
    }
  }
}

// ---- upsample + seed + calc + init occ_out=occ_i (fused; no conf zeroing) ----
static __global__ __launch_bounds__(256) void k_resize_b0(
    const float* __restrict__ prev,
    const unsigned char* __restrict__ calc_prev,
    float* __restrict__ occ_i, float* __restrict__ occ_out,
    unsigned char* __restrict__ bnd0, unsigned char* __restrict__ calc_out,
    int R, int Rp)
{
  const unsigned int n = (unsigned int)R * (unsigned int)R * (unsigned int)R;
  unsigned int gid = blockIdx.x * 256u + threadIdx.x;
  if (gid >= n) return;
  int c = (int)(gid % (unsigned int)R);
  unsigned int r = gid / (unsigned int)R;
  int b = (int)(r % (unsigned int)R);
  int a = (int)(r / (unsigned int)R);
  int a0 = a >> 1, da = a & 1;
  int b0i = b >> 1, db = b & 1;
  int c0 = c >> 1, dc = c & 1;
  float sum = 0.0f;
  int cnt = 0;
  const int tot = (da + 1) * (db + 1) * (dc + 1);
  for (int dz = 0; dz <= da; ++dz)
    for (int dy = 0; dy <= db; ++dy)
      for (int dx = 0; dx <= dc; ++dx){
        float v = prev[((unsigned int)(a0 + dz) * (unsigned int)Rp + (unsigned int)(b0i + dy)) * (unsigned int)Rp + (unsigned int)(c0 + dx)];
        sum += v;
        cnt += (v > 0.5f) ? 1 : 0;
      }
  float oi = sum / (float)tot;
  occ_i[gid] = oi;
  occ_out[gid] = oi;
  bnd0[gid] = (cnt > 0 && cnt < tot) ? 1 : 0;
  calc_out[gid] = ((da | db | dc) == 0)
      ? calc_prev[((unsigned int)a0 * (unsigned int)Rp + (unsigned int)b0i) * (unsigned int)Rp + (unsigned int)c0]
      : (unsigned char)0;
}

// ---- dense variant with mism + occ_out init (R=33 path) ----
static __global__ __launch_bounds__(256) void k_resize_boundary(
    const float* __restrict__ prev, const float* __restrict__ occ_true,
    const unsigned char* __restrict__ calc_prev,
    float* __restrict__ occ_i, float* __restrict__ occ_out,
    unsigned char* __restrict__ bnd0,
    unsigned char* __restrict__ mism, unsigned char* __restrict__ calc_out,
    int R, int Rp)
{
  const unsigned int n = (unsigned int)R * (unsigned int)R * (unsigned int)R;
  unsigned int gid = blockIdx.x * 256u + threadIdx.x;
  if (gid >= n) return;
  int c = (int)(gid % (unsigned int)R);
  unsigned int r = gid / (unsigned int)R;
  int b = (int)(r % (unsigned int)R);
  int a = (int)(r / (unsigned int)R);
  int a0 = a >> 1, da = a & 1;
  int b0i = b >> 1, db = b & 1;
  int c0 = c >> 1, dc = c & 1;
  float sum = 0.0f;
  int cnt = 0;
  const int tot = (da + 1) * (db + 1) * (dc + 1);
  for (int dz = 0; dz <= da; ++dz)
    for (int dy = 0; dy <= db; ++dy)
      for (int dx = 0; dx <= dc; ++dx){
        float v = prev[((unsigned int)(a0 + dz) * (unsigned int)Rp + (unsigned int)(b0i + dy)) * (unsigned int)Rp + (unsigned int)(c0 + dx)];
        sum += v;
        cnt += (v > 0.5f) ? 1 : 0;
      }
  float oi = sum / (float)tot;
  occ_i[gid] = oi;
  occ_out[gid] = oi;
  bnd0[gid] = (cnt > 0 && cnt < tot) ? 1 : 0;
  mism[gid] = ((oi - 0.5f) * (occ_true[gid] - 0.5f) < 0.0f) ? 1 : 0;
  calc_out[gid] = ((da | db | dc) == 0)
      ? calc_prev[((unsigned int)a0 * (unsigned int)Rp + (unsigned int)b0i) * (unsigned int)Rp + (unsigned int)c0]
      : (unsigned char)0;
}

// ---- tiled 7^3 box dilation (separable in LDS) + per-tile count ----
static __global__ __launch_bounds__(512) void k_dil7_tiled(
    const unsigned char* __restrict__ in, unsigned char* __restrict__ outp,
    unsigned int* __restrict__ bcnt, int R, int T)
{
  __shared__ unsigned char s0[14*14*14];
  __shared__ unsigned char s1[14*14*8];
  __shared__ unsigned char s2[14*8*8];
  __shared__ unsigned int wc[8];
  const int tile = blockIdx.x;
  const int tz = tile / (T*T);
  const int ty = (tile / T) % T;
  const int tx = tile % T;
  const int bz = tz*8 - 3, by = ty*8 - 3, bx = tx*8 - 3;
  const int t = threadIdx.x;
  for (int i = t; i < 14*14*14; i += 512){
    int lz = i / 196, rr = i % 196, ly = rr / 14, lx = rr % 14;
    int gz = bz + lz, gy = by + ly, gx = bx + lx;
    unsigned char v = 0;
    if (gz >= 0 && gz < R && gy >= 0 && gy < R && gx >= 0 && gx < R)
      v = in[((unsigned int)gz * (unsigned int)R + (unsigned int)gy) * (unsigned int)R + (unsigned int)gx];
    s0[i] = v;
  }
  __syncthreads();
  for (int i = t; i < 14*14*8; i += 512){
    int lz = i / 112, rr = i % 112, ly = rr / 8, lx = rr % 8;
    const unsigned char* p = &s0[lz*196 + ly*14 + lx];
    s1[i] = (unsigned char)(p[0]|p[1]|p[2]|p[3]|p[4]|p[5]|p[6]);
  }
  __syncthreads();
  for (int i = t; i < 14*8*8; i += 512){
    int lz = i / 64, rr = i % 64, ly = rr / 8, lx = rr % 8;
    const unsigned char* p = &s1[lz*112 + ly*8 + lx];
    s2[i] = (unsigned char)(p[0]|p[8]|p[16]|p[24]|p[32]|p[40]|p[48]);
  }
  __syncthreads();
  int lz = t >> 6, ly = (t >> 3) & 7, lx = t & 7;
  const unsigned char* p = &s2[lz*64 + ly*8 + lx];
  int m = p[0]|p[64]|p[128]|p[192]|p[256]|p[320]|p[384];
  int gz = tz*8 + lz, gy = ty*8 + ly, gx = tx*8 + lx;
  bool inb = (gz < R) && (gy < R) && (gx < R);
  if (inb) outp[((unsigned int)gz * (unsigned int)R + (unsigned int)gy) * (unsigned int)R + (unsigned int)gx]
      = (unsigned char)(m ? 1 : 0);
  unsigned long long bm = __ballot(inb && m);
  int w = t >> 6;
  if ((t & 63) == 0) wc[w] = (unsigned int)__popcll(bm);
  __syncthreads();
  if (t == 0) bcnt[blockIdx.x] = wc[0]+wc[1]+wc[2]+wc[3]+wc[4]+wc[5]+wc[6]+wc[7];
}

// single block, 1024 threads: exclusive scan of nb block counts
static __global__ __launch_bounds__(1024) void k_scan(
    unsigned int* __restrict__ bcnt, unsigned int nb, unsigned int* __restrict__ total)
{
  __shared__ unsigned int part[1024];
  const unsigned int t = threadIdx.x;
  const unsigned int chunk = (nb + 1023u) / 1024u;
  const unsigned int beg = t * chunk;
  const unsigned int end = (beg + chunk < nb) ? (beg + chunk) : nb;
  unsigned int s = 0;
  for (unsigned int i = beg; i < end; ++i) s += bcnt[i];
  part[t] = s;
  __syncthreads();
  for (int offd = 1; offd < 1024; offd <<= 1){
    unsigned int v = (t >= (unsigned int)offd) ? part[t - offd] : 0u;
    __syncthreads();
    part[t] += v;
    __syncthreads();
  }
  unsigned int run = (t == 0) ? 0u : part[t - 1];
  for (unsigned int i = beg; i < end; ++i){
    unsigned int v = bcnt[i];
    bcnt[i] = run;
    run += v;
  }
  if (t == 1023) *total = part[1023];
}

// ---- tile-indexed scatter (matches k_dil7_tiled's bcnt decomposition) ----
static __global__ __launch_bounds__(512) void k_scatter_tiled(
    const unsigned char* __restrict__ cand, const unsigned int* __restrict__ boff,
    int* __restrict__ idxl, int R, int T)
{
  __shared__ unsigned int wbase[8];
  const int tile = blockIdx.x;
  const int tz = tile / (T*T), ty = (tile / T) % T, tx = tile % T;
  const int t = threadIdx.x;
  int lz = t >> 6, ly = (t >> 3) & 7, lx = t & 7;
  int gz = tz*8 + lz, gy = ty*8 + ly, gx = tx*8 + lx;
  bool inb = (gz < R) && (gy < R) && (gx < R);
  int gid = inb ? (int)(((unsigned int)gz * (unsigned int)R + (unsigned int)gy) * (unsigned int)R + (unsigned int)gx) : 0;
  bool pred = inb && (cand[gid] != 0);
  unsigned long long m = __ballot(pred);
  int w = t >> 6, lane = t & 63;
  if (lane == 0) wbase[w] = (unsigned int)__popcll(m);
  __syncthreads();
  if (t == 0){
    unsigned int run = boff[blockIdx.x];
    for (int i = 0; i < 8; ++i){ unsigned int v = wbase[i]; wbase[i] = run; run += v; }
  }
  __syncthreads();
  if (pred){
    int pre = __popcll(m & ((1ull << lane) - 1ull));
    idxl[wbase[w] + (unsigned int)pre] = gid;
  }
}

// ---- fused 3-step dilate/conflict propagation, tiled in LDS ----
// Replaces 3 dilate dispatches. 8^3 core + halo3 = 14^3 staged (b0, calc,
// mism). Step k valid at halo(3-k); upd = calc flipped 0->1; commits
// occ_out = occ_true at updated core cells. OOB: b0=0, calc=1 -> inert.
// mism read only where nb=1 (subset of candidate set C where mism is valid).
static __global__ __launch_bounds__(512) void k_dilate3_tiled(
    const unsigned char* __restrict__ b0,
    const unsigned char* __restrict__ mism,
    unsigned char* __restrict__ calc,
    const float* __restrict__ occ_true,
    float* __restrict__ occ_out,
    int R, int T)
{
  __shared__ unsigned char sC[14*14*14];  // conf ping (starts as b0)
  __shared__ unsigned char sD[14*14*14];  // conf pong
  __shared__ unsigned char sK[14*14*14];  // calc (in-place updated)
  __shared__ unsigned char sM[14*14*14];  // mism
  __shared__ int s_any;
  const int tile = blockIdx.x;
  const int tz = tile / (T*T), ty = (tile / T) % T, tx = tile % T;
  const int bz = tz*8 - 3, by = ty*8 - 3, bx = tx*8 - 3;
  const int t = threadIdx.x;
  if (t == 0) s_any = 0;
  __syncthreads();
  int any = 0;
  for (int i = t; i < 2744; i += 512){
    int lz = i / 196, rr = i % 196, ly = rr / 14, lx = rr % 14;
    int gz = bz + lz, gy = by + ly, gx = bx + lx;
    bool in = (gz >= 0 && gz < R && gy >= 0 && gy < R && gx >= 0 && gx < R);
    unsigned int g = in ? (((unsigned int)gz * (unsigned int)R + (unsigned int)gy) * (unsigned int)R + (unsigned int)gx) : 0u;
    unsigned char v0 = in ? b0[g] : (unsigned char)0;
    sC[i] = v0; any |= v0;
    sK[i] = in ? calc[g] : (unsigned char)1;
    sM[i] = in ? mism[g] : (unsigned char)0;
  }
  if (any) s_any = 1;      // benign multi-writer (all write 1)
  __syncthreads();
  if (!s_any) return;      // no seed anywhere in halo: nothing can change

  // core cell of this thread
  const int clz = 3 + (t >> 6), cly = 3 + ((t >> 3) & 7), clx = 3 + (t & 7);
  const int cp = clz*196 + cly*14 + clx;
  const unsigned char calc0 = sK[cp];
  __syncthreads();         // calc0 reads complete before step-1 writes sK

  // step 1: conf1 over [1,13)^3, src = sC (b0), dst = sD
  for (int i = t; i < 1728; i += 512){
    int lz = i / 144 + 1, rr = i % 144, ly = rr / 12 + 1, lx = rr % 12 + 1;
    int p = lz*196 + ly*14 + lx;
    int m = 0;
    #pragma unroll
    for (int dz = -1; dz <= 1; ++dz)
      #pragma unroll
      for (int dy = -1; dy <= 1; ++dy)
        #pragma unroll
        for (int dx = -1; dx <= 1; ++dx)
          m |= sC[p + dz*196 + dy*14 + dx];
    unsigned char nb = (m && !sK[p]) ? (unsigned char)1 : (unsigned char)0;
    sD[p] = (nb && sM[p]) ? (unsigned char)1 : (unsigned char)0;
    if (nb) sK[p] = 1;
  }
  __syncthreads();
  // step 2: conf2 over [2,12)^3, src = sD, dst = sC
  for (int i = t; i < 1000; i += 512){
    int lz = i / 100 + 2, rr = i % 100, ly = rr / 10 + 2, lx = rr % 10 + 2;
    int p = lz*196 + ly*14 + lx;
    int m = 0;
    #pragma unroll
    for (int dz = -1; dz <= 1; ++dz)
      #pragma unroll
      for (int dy = -1; dy <= 1; ++dy)
        #pragma unroll
        for (int dx = -1; dx <= 1; ++dx)
          m |= sD[p + dz*196 + dy*14 + dx];
    unsigned char nb = (m && !sK[p]) ? (unsigned char)1 : (unsigned char)0;
    sC[p] = (nb && sM[p]) ? (unsigned char)1 : (unsigned char)0;
    if (nb) sK[p] = 1;
  }
  __syncthreads();
  // step 3: core only, src = sC (conf2); conf3 not needed
  {
    int m = 0;
    #pragma unroll
    for (int dz = -1; dz <= 1; ++dz)
      #pragma unroll
      for (int dy = -1; dy <= 1; ++dy)
        #pragma unroll
        for (int dx = -1; dx <= 1; ++dx)
          m |= sC[cp + dz*196 + dy*14 + dx];
    if (m && !sK[cp]) sK[cp] = 1;
  }
  // write back core
  int gz = tz*8 + (clz - 3), gy = ty*8 + (cly - 3), gx = tx*8 + (clx - 3);
  if (gz < R && gy < R && gx < R){
    unsigned int g = ((unsigned int)gz * (unsigned int)R + (unsigned int)gy) * (unsigned int)R + (unsigned int)gx;
    unsigned char cf = sK[cp];
    calc[g] = cf;
    if (cf && !calc0) occ_out[g] = occ_true[g];   // upd = calc flipped
  }
}

extern "C" void kernel_launch(void* const* d_in, const int* in_sizes, int n_in,
                              void* d_out, int out_size, void* d_ws, size_t ws_size,
                              hipStream_t stream)
{
  const float* w1 = (const float*)d_in[0];
  const float* b1 = (const float*)d_in[1];
  const float* w2 = (const float*)d_in[2];
  const float* b2 = (const float*)d_in[3];
  const float* w3 = (const float*)d_in[4];
  const float* b3 = (const float*)d_in[5];
  float* out = (float*)d_out;

  const int NF = 129 * 129 * 129;  // 2146689
  const int NP = 65 * 65 * 65;
  char* ws = (char*)d_ws;
  size_t off = 0;
  auto alloc = [&](size_t bytes) -> void* {
    void* p = (void*)(ws + off);
    off += (bytes + 255) & ~(size_t)255;
    return p;
  };
  float* f_true  = (float*)alloc((size_t)NF * 4);
  float* f_occi  = (float*)alloc((size_t)NF * 4);
  float* f_prevA = (float*)alloc((size_t)NP * 4);
  float* f_prevB = (float*)alloc((size_t)NP * 4);
  float* f_w2t   = (float*)alloc((size_t)HH * HH * 4);
  int*   i_idx   = (int*)alloc((size_t)NF * 4);
  unsigned int* u_cnt  = (unsigned int*)alloc(256);
  unsigned int* u_bcnt = (unsigned int*)alloc(8448 * 4);
  unsigned char* b_b0    = (unsigned char*)alloc(NF);
  unsigned char* b_mism  = (unsigned char*)alloc(NF);
  unsigned char* b_calcA = (unsigned char*)alloc(NF);
  unsigned char* b_calcB = (unsigned char*)alloc(NF);
  unsigned char* b_cand  = (unsigned char*)alloc(NF);
  (void)ws_size;

  k_prep_w2t<<<16, 256, 0, stream>>>(w2, f_w2t);

  // Level 0: R=17 dense pair eval, calc=1 fused in.
  {
    int R = 17, s = 8;
    int n = R * R * R;
    int blocks = (n + 255) / 256;
    k_eval_mlp<<<blocks, 256, 0, stream>>>(w1, b1, f_w2t, b2, w3, b3, f_prevA, b_calcA, R, s);
  }

  int Rp = 17;
  float* prev = f_prevA;
  unsigned char* calcP = b_calcA;
  unsigned char* calcC = b_calcB;
  for (int li = 1; li <= 3; ++li){
    int R = 2 * Rp - 1;
    int s = 128 / (R - 1);
    unsigned int n = (unsigned int)R * (unsigned int)R * (unsigned int)R;
    int blocks = (int)((n + 255u) / 256u);
    const int T = (R + 7) / 8;
    const int tblocks = T * T * T;
    float* occ_out = (li == 3) ? out : ((prev == f_prevA) ? f_prevB : f_prevA);

    if (R == 33){
      // dense eval (low TLP suits pair core), then fused 3-step dilate
      k_eval_mlp<<<blocks, 256, 0, stream>>>(w1, b1, f_w2t, b2, w3, b3, f_true, (unsigned char*)nullptr, R, s);
      k_resize_boundary<<<blocks, 256, 0, stream>>>(prev, f_true, calcP, f_occi, occ_out, b_b0, b_mism, calcC, R, Rp);
      k_dilate3_tiled<<<tblocks, 512, 0, stream>>>(b_b0, b_mism, calcC, f_true, occ_out, R, T);
    } else {
      // sparse: eval only on C = dilate^3(seed); fused 3-step dilate
      k_resize_b0<<<blocks, 256, 0, stream>>>(prev, calcP, f_occi, occ_out, b_b0, calcC, R, Rp);
      k_dil7_tiled<<<tblocks, 512, 0, stream>>>(b_b0, b_cand, u_bcnt, R, T);
      k_scan<<<1, 1024, 0, stream>>>(u_bcnt, (unsigned int)tblocks, u_cnt);
      k_scatter_tiled<<<tblocks, 512, 0, stream>>>(b_cand, u_bcnt, i_idx, R, T);
      k_eval_sparse<<<blocks, 256, 0, stream>>>(
          w1, b1, f_w2t, b2, w3, b3, i_idx, u_cnt, f_occi, f_true, b_mism, R, s, n);
      k_dilate3_tiled<<<tblocks, 512, 0, stream>>>(b_b0, b_mism, calcC, f_true, occ_out, R, T);
    }

    prev = occ_out;
    unsigned char* tmpc = calcP; calcP = calcC; calcC = tmpc;
    Rp = R;
  }
  (void)in_sizes; (void)n_in; (void)out_size;
}

// Round 11
// 308.213 us; speedup vs baseline: 1.2556x; 1.2556x over previous
//
#include <hip/hip_runtime.h>

#define HH 64

// one-time: w2t[j*64+i] = w2[i*64+j]
static __global__ void k_prep_w2t(const float* __restrict__ w2, float* __restrict__ w2t){
  int t = blockIdx.x * 256 + threadIdx.x;   // 16 blocks x 256 = 4096
  w2t[t] = w2[(t & 63) * HH + (t >> 6)];
}

// ===================== pair-MLP core (LDS weights) ==========
// ~6.7k pts/us chip-wide, LDS-datapath-bound (8 ds_read_b128/wave-j).
__device__ __forceinline__ void mlp_pair(
    const float* __restrict__ sw1,   // LDS: x[64] y[64] z[64] b1[64]
    const float* __restrict__ sw2t,  // LDS: 4096
    const float* __restrict__ b2, const float* __restrict__ w3,
    const float* __restrict__ b3,
    float xA, float yA, float zA, float xB, float yB, float zB,
    float& outA, float& outB)
{
  const int ibase = ((threadIdx.x & 63) >> 5) * 32;
  float h1a[32], h1b[32];
  #pragma unroll
  for (int k = 0; k < 32; k += 4){
    const float4 wx = *(const float4*)&sw1[      ibase + k];
    const float4 wy = *(const float4*)&sw1[ 64 + ibase + k];
    const float4 wz = *(const float4*)&sw1[128 + ibase + k];
    const float4 bb = *(const float4*)&sw1[192 + ibase + k];
    h1a[k+0] = fmaxf(fmaf(xA,wx.x,fmaf(yA,wy.x,fmaf(zA,wz.x,bb.x))),0.f);
    h1a[k+1] = fmaxf(fmaf(xA,wx.y,fmaf(yA,wy.y,fmaf(zA,wz.y,bb.y))),0.f);
    h1a[k+2] = fmaxf(fmaf(xA,wx.z,fmaf(yA,wy.z,fmaf(zA,wz.z,bb.z))),0.f);
    h1a[k+3] = fmaxf(fmaf(xA,wx.w,fmaf(yA,wy.w,fmaf(zA,wz.w,bb.w))),0.f);
    h1b[k+0] = fmaxf(fmaf(xB,wx.x,fmaf(yB,wy.x,fmaf(zB,wz.x,bb.x))),0.f);
    h1b[k+1] = fmaxf(fmaf(xB,wx.y,fmaf(yB,wy.y,fmaf(zB,wz.y,bb.y))),0.f);
    h1b[k+2] = fmaxf(fmaf(xB,wx.z,fmaf(yB,wy.z,fmaf(zB,wz.z,bb.z))),0.f);
    h1b[k+3] = fmaxf(fmaf(xB,wx.w,fmaf(yB,wy.w,fmaf(zB,wz.w,bb.w))),0.f);
  }
  float oa = b3[0], ob = oa;
  #pragma unroll 1
  for (int j = 0; j < HH; ++j){
    const float4* wrow = (const float4*)&sw2t[j*HH + ibase];
    float a0 = 0.f, a1 = 0.f, c0 = 0.f, c1 = 0.f;
    #pragma unroll
    for (int q = 0; q < 8; q += 2){
      const float4 w0 = wrow[q];
      const float4 w1q = wrow[q+1];
      a0 = fmaf(h1a[4*q+0], w0.x, a0);
      a0 = fmaf(h1a[4*q+1], w0.y, a0);
      a0 = fmaf(h1a[4*q+2], w0.z, a0);
      a0 = fmaf(h1a[4*q+3], w0.w, a0);
      a1 = fmaf(h1a[4*q+4], w1q.x, a1);
      a1 = fmaf(h1a[4*q+5], w1q.y, a1);
      a1 = fmaf(h1a[4*q+6], w1q.z, a1);
      a1 = fmaf(h1a[4*q+7], w1q.w, a1);
      c0 = fmaf(h1b[4*q+0], w0.x, c0);
      c0 = fmaf(h1b[4*q+1], w0.y, c0);
      c0 = fmaf(h1b[4*q+2], w0.z, c0);
      c0 = fmaf(h1b[4*q+3], w0.w, c0);
      c1 = fmaf(h1b[4*q+4], w1q.x, c1);
      c1 = fmaf(h1b[4*q+5], w1q.y, c1);
      c1 = fmaf(h1b[4*q+6], w1q.z, c1);
      c1 = fmaf(h1b[4*q+7], w1q.w, c1);
    }
    float accA = a0 + a1, accB = c0 + c1;
    accA += __shfl_xor(accA, 32);
    accB += __shfl_xor(accB, 32);
    const float bj = b2[j], wj = w3[j];
    oa = fmaf(fmaxf(accA + bj, 0.f), wj, oa);
    ob = fmaf(fmaxf(accB + bj, 0.f), wj, ob);
  }
  outA = 1.f / (1.f + expf(-oa));
  outB = 1.f / (1.f + expf(-ob));
}

#define STAGE_WEIGHTS()                                            \
  __shared__ float sw1[4*HH];                                      \
  __shared__ float sw2t[HH*HH];                                    \
  {                                                                \
    const int t0 = threadIdx.x;                                    \
    if (t0 < 3*HH) sw1[t0] = w1[t0];                               \
    else sw1[t0] = b1[t0 - 3*HH];                                  \
    const float4* s4 = (const float4*)w2t;                         \
    float4* d4 = (float4*)sw2t;                                    \
    for (int i4 = t0; i4 < HH*HH/4; i4 += 256) d4[i4] = s4[i4];    \
    __syncthreads();                                               \
  }

// ---------------- dense pair eval (R=17, 33); optional calc=1 write ----------
static __global__ __launch_bounds__(256)
__attribute__((amdgpu_waves_per_eu(4,4)))
void k_eval_mlp(
    const float* __restrict__ w1, const float* __restrict__ b1,
    const float* __restrict__ w2t, const float* __restrict__ b2,
    const float* __restrict__ w3, const float* __restrict__ b3,
    float* __restrict__ out, unsigned char* __restrict__ calc1,
    int R, int s)
{
  STAGE_WEIGHTS();
  const unsigned int n = (unsigned int)R * (unsigned int)R * (unsigned int)R;
  const int lane = threadIdx.x & 63;
  const int wid = threadIdx.x >> 6;
  const unsigned int base = blockIdx.x * 256u + (unsigned int)(wid * 64 + (lane & 31));
  const unsigned int pidA = base < n ? base : (n - 1u);
  const unsigned int pB = base + 32u;
  const unsigned int pidB = pB < n ? pB : (n - 1u);
  const float inv129x2 = 2.0f / 129.0f;
  unsigned int cA = pidA % (unsigned int)R, rA = pidA / (unsigned int)R;
  unsigned int cB = pidB % (unsigned int)R, rB = pidB / (unsigned int)R;
  const float xA = ((float)(cA * (unsigned int)s) + 0.5f) * inv129x2 - 1.0f;
  const float yA = ((float)((rA % (unsigned int)R) * (unsigned int)s) + 0.5f) * inv129x2 - 1.0f;
  const float zA = ((float)((rA / (unsigned int)R) * (unsigned int)s) + 0.5f) * inv129x2 - 1.0f;
  const float xB = ((float)(cB * (unsigned int)s) + 0.5f) * inv129x2 - 1.0f;
  const float yB = ((float)((rB % (unsigned int)R) * (unsigned int)s) + 0.5f) * inv129x2 - 1.0f;
  const float zB = ((float)((rB / (unsigned int)R) * (unsigned int)s) + 0.5f) * inv129x2 - 1.0f;
  float oA, oB;
  mlp_pair(sw1, sw2t, b2, w3, b3, xA, yA, zA, xB, yB, zB, oA, oB);
  if ((threadIdx.x & 63) < 32){
    if (base < n){ out[pidA] = oA; if (calc1) calc1[pidA] = 1; }
    if (pB < n)  { out[pidB] = oB; if (calc1) calc1[pidB] = 1; }
  }
}

// ------------- sparse pair eval over compacted index list (R=65, 129) --------
static __global__ __launch_bounds__(256)
__attribute__((amdgpu_waves_per_eu(4,4)))
void k_eval_sparse(
    const float* __restrict__ w1, const float* __restrict__ b1,
    const float* __restrict__ w2t, const float* __restrict__ b2,
    const float* __restrict__ w3, const float* __restrict__ b3,
    const int* __restrict__ idxl, const unsigned int* __restrict__ cnt,
    const float* __restrict__ occ_i,
    float* __restrict__ out, unsigned char* __restrict__ mism,
    int R, int s, unsigned int n)
{
  unsigned int count = *cnt;
  if (count > n) count = n;               // guard vs stale ws during profiling replay
  if (blockIdx.x * 256u >= count) return;
  STAGE_WEIGHTS();
  const int lane = threadIdx.x & 63;
  const int wid = threadIdx.x >> 6;
  const unsigned int slotA = blockIdx.x * 256u + (unsigned int)(wid * 64 + (lane & 31));
  const unsigned int slotB = slotA + 32u;
  const bool vA = slotA < count, vB = slotB < count;
  const unsigned int pidA = (unsigned int)idxl[vA ? slotA : 0];
  const unsigned int pidB = (unsigned int)idxl[vB ? slotB : 0];
  const float inv129x2 = 2.0f / 129.0f;
  unsigned int cA = pidA % (unsigned int)R, rA = pidA / (unsigned int)R;
  unsigned int cB = pidB % (unsigned int)R, rB = pidB / (unsigned int)R;
  const float xA = ((float)(cA * (unsigned int)s) + 0.5f) * inv129x2 - 1.0f;
  const float yA = ((float)((rA % (unsigned int)R) * (unsigned int)s) + 0.5f) * inv129x2 - 1.0f;
  const float zA = ((float)((rA / (unsigned int)R) * (unsigned int)s) + 0.5f) * inv129x2 - 1.0f;
  const float xB = ((float)(cB * (unsigned int)s) + 0.5f) * inv129x2 - 1.0f;
  const float yB = ((float)((rB % (unsigned int)R) * (unsigned int)s) + 0.5f) * inv129x2 - 1.0f;
  const float zB = ((float)((rB / (unsigned int)R) * (unsigned int)s) + 0.5f) * inv129x2 - 1.0f;
  float oA, oB;
  mlp_pair(sw1, sw2t, b2, w3, b3, xA, yA, zA, xB, yB, zB, oA, oB);
  if ((threadIdx.x & 63) < 32){
    if (vA){
      out[pidA] = oA;
      mism[pidA] = ((occ_i[pidA] - 0.5f) * (oA - 0.5f) < 0.0f) ? (unsigned char)1 : (unsigned char)0;
    }
    if (vB){
      out[pidB] = oB;
      mism[pidB] = ((occ_i[pidB] - 0.5f) * (oB - 0.5f) < 0.0f) ? (unsigned char)1 : (unsigned char)0;
    }
  }
}

// ---- upsample + seed + calc + init occ_out=occ_i + zero conf arrays ----
static __global__ __launch_bounds__(256) void k_resize_b0(
    const float* __restrict__ prev,
    const unsigned char* __restrict__ calc_prev,
    float* __restrict__ occ_i, float* __restrict__ occ_out,
    unsigned char* __restrict__ bnd0, unsigned char* __restrict__ calc_out,
    unsigned char* __restrict__ confA, unsigned char* __restrict__ confB,
    int R, int Rp)
{
  const unsigned int n = (unsigned int)R * (unsigned int)R * (unsigned int)R;
  unsigned int gid = blockIdx.x * 256u + threadIdx.x;
  if (gid >= n) return;
  int c = (int)(gid % (unsigned int)R);
  unsigned int r = gid / (unsigned int)R;
  int b = (int)(r % (unsigned int)R);
  int a = (int)(r / (unsigned int)R);
  int a0 = a >> 1, da = a & 1;
  int b0i = b >> 1, db = b & 1;
  int c0 = c >> 1, dc = c & 1;
  float sum = 0.0f;
  int cnt = 0;
  const int tot = (da + 1) * (db + 1) * (dc + 1);
  for (int dz = 0; dz <= da; ++dz)
    for (int dy = 0; dy <= db; ++dy)
      for (int dx = 0; dx <= dc; ++dx){
        float v = prev[((unsigned int)(a0 + dz) * (unsigned int)Rp + (unsigned int)(b0i + dy)) * (unsigned int)Rp + (unsigned int)(c0 + dx)];
        sum += v;
        cnt += (v > 0.5f) ? 1 : 0;
      }
  float oi = sum / (float)tot;
  occ_i[gid] = oi;
  occ_out[gid] = oi;
  bnd0[gid] = (cnt > 0 && cnt < tot) ? 1 : 0;
  calc_out[gid] = ((da | db | dc) == 0)
      ? calc_prev[((unsigned int)a0 * (unsigned int)Rp + (unsigned int)b0i) * (unsigned int)Rp + (unsigned int)c0]
      : (unsigned char)0;
  confA[gid] = 0; confB[gid] = 0;
}

// ---- dense variant with mism + occ_out init (R=33 path) ----
static __global__ __launch_bounds__(256) void k_resize_boundary(
    const float* __restrict__ prev, const float* __restrict__ occ_true,
    const unsigned char* __restrict__ calc_prev,
    float* __restrict__ occ_i, float* __restrict__ occ_out,
    unsigned char* __restrict__ bnd0,
    unsigned char* __restrict__ mism, unsigned char* __restrict__ calc_out,
    int R, int Rp)
{
  const unsigned int n = (unsigned int)R * (unsigned int)R * (unsigned int)R;
  unsigned int gid = blockIdx.x * 256u + threadIdx.x;
  if (gid >= n) return;
  int c = (int)(gid % (unsigned int)R);
  unsigned int r = gid / (unsigned int)R;
  int b = (int)(r % (unsigned int)R);
  int a = (int)(r / (unsigned int)R);
  int a0 = a >> 1, da = a & 1;
  int b0i = b >> 1, db = b & 1;
  int c0 = c >> 1, dc = c & 1;
  float sum = 0.0f;
  int cnt = 0;
  const int tot = (da + 1) * (db + 1) * (dc + 1);
  for (int dz = 0; dz <= da; ++dz)
    for (int dy = 0; dy <= db; ++dy)
      for (int dx = 0; dx <= dc; ++dx){
        float v = prev[((unsigned int)(a0 + dz) * (unsigned int)Rp + (unsigned int)(b0i + dy)) * (unsigned int)Rp + (unsigned int)(c0 + dx)];
        sum += v;
        cnt += (v > 0.5f) ? 1 : 0;
      }
  float oi = sum / (float)tot;
  occ_i[gid] = oi;
  occ_out[gid] = oi;
  bnd0[gid] = (cnt > 0 && cnt < tot) ? 1 : 0;
  mism[gid] = ((oi - 0.5f) * (occ_true[gid] - 0.5f) < 0.0f) ? 1 : 0;
  calc_out[gid] = ((da | db | dc) == 0)
      ? calc_prev[((unsigned int)a0 * (unsigned int)Rp + (unsigned int)b0i) * (unsigned int)Rp + (unsigned int)c0]
      : (unsigned char)0;
}

// ---- tiled 7^3 box dilation (separable in LDS) + per-tile count ----
static __global__ __launch_bounds__(512) void k_dil7_tiled(
    const unsigned char* __restrict__ in, unsigned char* __restrict__ outp,
    unsigned int* __restrict__ bcnt, int R, int T)
{
  __shared__ unsigned char s0[14*14*14];
  __shared__ unsigned char s1[14*14*8];
  __shared__ unsigned char s2[14*8*8];
  __shared__ unsigned int wc[8];
  const int tile = blockIdx.x;
  const int tz = tile / (T*T);
  const int ty = (tile / T) % T;
  const int tx = tile % T;
  const int bz = tz*8 - 3, by = ty*8 - 3, bx = tx*8 - 3;
  const int t = threadIdx.x;
  for (int i = t; i < 14*14*14; i += 512){
    int lz = i / 196, rr = i % 196, ly = rr / 14, lx = rr % 14;
    int gz = bz + lz, gy = by + ly, gx = bx + lx;
    unsigned char v = 0;
    if (gz >= 0 && gz < R && gy >= 0 && gy < R && gx >= 0 && gx < R)
      v = in[((unsigned int)gz * (unsigned int)R + (unsigned int)gy) * (unsigned int)R + (unsigned int)gx];
    s0[i] = v;
  }
  __syncthreads();
  for (int i = t; i < 14*14*8; i += 512){
    int lz = i / 112, rr = i % 112, ly = rr / 8, lx = rr % 8;
    const unsigned char* p = &s0[lz*196 + ly*14 + lx];
    s1[i] = (unsigned char)(p[0]|p[1]|p[2]|p[3]|p[4]|p[5]|p[6]);
  }
  __syncthreads();
  for (int i = t; i < 14*8*8; i += 512){
    int lz = i / 64, rr = i % 64, ly = rr / 8, lx = rr % 8;
    const unsigned char* p = &s1[lz*112 + ly*8 + lx];
    s2[i] = (unsigned char)(p[0]|p[8]|p[16]|p[24]|p[32]|p[40]|p[48]);
  }
  __syncthreads();
  int lz = t >> 6, ly = (t >> 3) & 7, lx = t & 7;
  const unsigned char* p = &s2[lz*64 + ly*8 + lx];
  int m = p[0]|p[64]|p[128]|p[192]|p[256]|p[320]|p[384];
  int gz = tz*8 + lz, gy = ty*8 + ly, gx = tx*8 + lx;
  bool inb = (gz < R) && (gy < R) && (gx < R);
  if (inb) outp[((unsigned int)gz * (unsigned int)R + (unsigned int)gy) * (unsigned int)R + (unsigned int)gx]
      = (unsigned char)(m ? 1 : 0);
  unsigned long long bm = __ballot(inb && m);
  int w = t >> 6;
  if ((t & 63) == 0) wc[w] = (unsigned int)__popcll(bm);
  __syncthreads();
  if (t == 0) bcnt[blockIdx.x] = wc[0]+wc[1]+wc[2]+wc[3]+wc[4]+wc[5]+wc[6]+wc[7];
}

// single block, 1024 threads: exclusive scan of nb block counts
static __global__ __launch_bounds__(1024) void k_scan(
    unsigned int* __restrict__ bcnt, unsigned int nb, unsigned int* __restrict__ total)
{
  __shared__ unsigned int part[1024];
  const unsigned int t = threadIdx.x;
  const unsigned int chunk = (nb + 1023u) / 1024u;
  const unsigned int beg = t * chunk;
  const unsigned int end = (beg + chunk < nb) ? (beg + chunk) : nb;
  unsigned int s = 0;
  for (unsigned int i = beg; i < end; ++i) s += bcnt[i];
  part[t] = s;
  __syncthreads();
  for (int offd = 1; offd < 1024; offd <<= 1){
    unsigned int v = (t >= (unsigned int)offd) ? part[t - offd] : 0u;
    __syncthreads();
    part[t] += v;
    __syncthreads();
  }
  unsigned int run = (t == 0) ? 0u : part[t - 1];
  for (unsigned int i = beg; i < end; ++i){
    unsigned int v = bcnt[i];
    bcnt[i] = run;
    run += v;
  }
  if (t == 1023) *total = part[1023];
}

// ---- tile-indexed scatter (matches k_dil7_tiled's bcnt decomposition) ----
static __global__ __launch_bounds__(512) void k_scatter_tiled(
    const unsigned char* __restrict__ cand, const unsigned int* __restrict__ boff,
    int* __restrict__ idxl, int R, int T)
{
  __shared__ unsigned int wbase[8];
  const int tile = blockIdx.x;
  const int tz = tile / (T*T), ty = (tile / T) % T, tx = tile % T;
  const int t = threadIdx.x;
  int lz = t >> 6, ly = (t >> 3) & 7, lx = t & 7;
  int gz = tz*8 + lz, gy = ty*8 + ly, gx = tx*8 + lx;
  bool inb = (gz < R) && (gy < R) && (gx < R);
  int gid = inb ? (int)(((unsigned int)gz * (unsigned int)R + (unsigned int)gy) * (unsigned int)R + (unsigned int)gx) : 0;
  bool pred = inb && (cand[gid] != 0);
  unsigned long long m = __ballot(pred);
  int w = t >> 6, lane = t & 63;
  if (lane == 0) wbase[w] = (unsigned int)__popcll(m);
  __syncthreads();
  if (t == 0){
    unsigned int run = boff[blockIdx.x];
    for (int i = 0; i < 8; ++i){ unsigned int v = wbase[i]; wbase[i] = run; run += v; }
  }
  __syncthreads();
  if (pred){
    int pre = __popcll(m & ((1ull << lane) - 1ull));
    idxl[wbase[w] + (unsigned int)pre] = gid;
  }
}

// ---- sparse dilate-step over cand list; commits occ_true at calc-flip ----
// nb = dilate(src) & ~calc ; calc|=nb ; occ_out=occ_true where nb ;
// conf_out = nb & mism. A point flips at most once across the 3 steps, so
// committing at flip time == r8's deferred upd-based commit. conf arrays
// pre-zeroed in k_resize_b0 (neighbor reads reach d^4 \ d^3).
static __global__ __launch_bounds__(256) void k_dilate_sparse(
    const int* __restrict__ idxl, const unsigned int* __restrict__ cnt,
    const unsigned char* __restrict__ src, const unsigned char* __restrict__ mism,
    unsigned char* __restrict__ calc, unsigned char* __restrict__ conf_out,
    int R, const float* __restrict__ occ_true, float* __restrict__ occ_out,
    unsigned int n)
{
  unsigned int count = *cnt;
  if (count > n) count = n;
  for (unsigned int slot = blockIdx.x * 256u + threadIdx.x; slot < count;
       slot += gridDim.x * 256u){
    int gid = idxl[slot];
    int c = gid % R;
    int r = gid / R;
    int b = r % R;
    int a = r / R;
    int m = 0;
    for (int dz = -1; dz <= 1; ++dz){
      int az = a + dz; if (az < 0 || az >= R) continue;
      for (int dy = -1; dy <= 1; ++dy){
        int by = b + dy; if (by < 0 || by >= R) continue;
        for (int dx = -1; dx <= 1; ++dx){
          int cx = c + dx; if (cx < 0 || cx >= R) continue;
          m |= src[(az * R + by) * R + cx];
        }
      }
    }
    unsigned char nb = (m && !calc[gid]) ? (unsigned char)1 : (unsigned char)0;
    conf_out[gid] = (nb && mism[gid]) ? (unsigned char)1 : (unsigned char)0;
    if (nb){
      calc[gid] = 1;
      occ_out[gid] = occ_true[gid];
    }
  }
}

// ---- fused 3-step dilate/conflict, tiled in LDS — R=33 ONLY (125 tiles).
// At 129 this is fetch-bound (5.4x halo staging of 4 byte arrays = 105us,
// r10); at 33's tile count the staging is trivial and it saves 2 dispatches.
static __global__ __launch_bounds__(512) void k_dilate3_tiled(
    const unsigned char* __restrict__ b0,
    const unsigned char* __restrict__ mism,
    unsigned char* __restrict__ calc,
    const float* __restrict__ occ_true,
    float* __restrict__ occ_out,
    int R, int T)
{
  __shared__ unsigned char sC[14*14*14];
  __shared__ unsigned char sD[14*14*14];
  __shared__ unsigned char sK[14*14*14];
  __shared__ unsigned char sM[14*14*14];
  __shared__ int s_any;
  const int tile = blockIdx.x;
  const int tz = tile / (T*T), ty = (tile / T) % T, tx = tile % T;
  const int bz = tz*8 - 3, by = ty*8 - 3, bx = tx*8 - 3;
  const int t = threadIdx.x;
  if (t == 0) s_any = 0;
  __syncthreads();
  int any = 0;
  for (int i = t; i < 2744; i += 512){
    int lz = i / 196, rr = i % 196, ly = rr / 14, lx = rr % 14;
    int gz = bz + lz, gy = by + ly, gx = bx + lx;
    bool in = (gz >= 0 && gz < R && gy >= 0 && gy < R && gx >= 0 && gx < R);
    unsigned int g = in ? (((unsigned int)gz * (unsigned int)R + (unsigned int)gy) * (unsigned int)R + (unsigned int)gx) : 0u;
    unsigned char v0 = in ? b0[g] : (unsigned char)0;
    sC[i] = v0; any |= v0;
    sK[i] = in ? calc[g] : (unsigned char)1;
    sM[i] = in ? mism[g] : (unsigned char)0;
  }
  if (any) s_any = 1;
  __syncthreads();
  if (!s_any) return;

  const int clz = 3 + (t >> 6), cly = 3 + ((t >> 3) & 7), clx = 3 + (t & 7);
  const int cp = clz*196 + cly*14 + clx;
  const unsigned char calc0 = sK[cp];
  __syncthreads();

  for (int i = t; i < 1728; i += 512){
    int lz = i / 144 + 1, rr = i % 144, ly = rr / 12 + 1, lx = rr % 12 + 1;
    int p = lz*196 + ly*14 + lx;
    int m = 0;
    #pragma unroll
    for (int dz = -1; dz <= 1; ++dz)
      #pragma unroll
      for (int dy = -1; dy <= 1; ++dy)
        #pragma unroll
        for (int dx = -1; dx <= 1; ++dx)
          m |= sC[p + dz*196 + dy*14 + dx];
    unsigned char nb = (m && !sK[p]) ? (unsigned char)1 : (unsigned char)0;
    sD[p] = (nb && sM[p]) ? (unsigned char)1 : (unsigned char)0;
    if (nb) sK[p] = 1;
  }
  __syncthreads();
  for (int i = t; i < 1000; i += 512){
    int lz = i / 100 + 2, rr = i % 100, ly = rr / 10 + 2, lx = rr % 10 + 2;
    int p = lz*196 + ly*14 + lx;
    int m = 0;
    #pragma unroll
    for (int dz = -1; dz <= 1; ++dz)
      #pragma unroll
      for (int dy = -1; dy <= 1; ++dy)
        #pragma unroll
        for (int dx = -1; dx <= 1; ++dx)
          m |= sD[p + dz*196 + dy*14 + dx];
    unsigned char nb = (m && !sK[p]) ? (unsigned char)1 : (unsigned char)0;
    sC[p] = (nb && sM[p]) ? (unsigned char)1 : (unsigned char)0;
    if (nb) sK[p] = 1;
  }
  __syncthreads();
  {
    int m = 0;
    #pragma unroll
    for (int dz = -1; dz <= 1; ++dz)
      #pragma unroll
      for (int dy = -1; dy <= 1; ++dy)
        #pragma unroll
        for (int dx = -1; dx <= 1; ++dx)
          m |= sC[cp + dz*196 + dy*14 + dx];
    if (m && !sK[cp]) sK[cp] = 1;
  }
  int gz = tz*8 + (clz - 3), gy = ty*8 + (cly - 3), gx = tx*8 + (clx - 3);
  if (gz < R && gy < R && gx < R){
    unsigned int g = ((unsigned int)gz * (unsigned int)R + (unsigned int)gy) * (unsigned int)R + (unsigned int)gx;
    unsigned char cf = sK[cp];
    calc[g] = cf;
    if (cf && !calc0) occ_out[g] = occ_true[g];
  }
}

extern "C" void kernel_launch(void* const* d_in, const int* in_sizes, int n_in,
                              void* d_out, int out_size, void* d_ws, size_t ws_size,
                              hipStream_t stream)
{
  const float* w1 = (const float*)d_in[0];
  const float* b1 = (const float*)d_in[1];
  const float* w2 = (const float*)d_in[2];
  const float* b2 = (const float*)d_in[3];
  const float* w3 = (const float*)d_in[4];
  const float* b3 = (const float*)d_in[5];
  float* out = (float*)d_out;

  const int NF = 129 * 129 * 129;  // 2146689
  const int NP = 65 * 65 * 65;
  char* ws = (char*)d_ws;
  size_t off = 0;
  auto alloc = [&](size_t bytes) -> void* {
    void* p = (void*)(ws + off);
    off += (bytes + 255) & ~(size_t)255;
    return p;
  };
  float* f_true  = (float*)alloc((size_t)NF * 4);
  float* f_occi  = (float*)alloc((size_t)NF * 4);
  float* f_prevA = (float*)alloc((size_t)NP * 4);
  float* f_prevB = (float*)alloc((size_t)NP * 4);
  float* f_w2t   = (float*)alloc((size_t)HH * HH * 4);
  int*   i_idx   = (int*)alloc((size_t)NF * 4);
  unsigned int* u_cnt  = (unsigned int*)alloc(256);
  unsigned int* u_bcnt = (unsigned int*)alloc(8448 * 4);
  unsigned char* b_b0    = (unsigned char*)alloc(NF);
  unsigned char* b_mism  = (unsigned char*)alloc(NF);
  unsigned char* b_confA = (unsigned char*)alloc(NF);
  unsigned char* b_confB = (unsigned char*)alloc(NF);
  unsigned char* b_calcA = (unsigned char*)alloc(NF);
  unsigned char* b_calcB = (unsigned char*)alloc(NF);
  unsigned char* b_cand  = (unsigned char*)alloc(NF);
  (void)ws_size;

  k_prep_w2t<<<16, 256, 0, stream>>>(w2, f_w2t);

  // Level 0: R=17 dense pair eval, calc=1 fused in.
  {
    int R = 17, s = 8;
    int n = R * R * R;
    int blocks = (n + 255) / 256;
    k_eval_mlp<<<blocks, 256, 0, stream>>>(w1, b1, f_w2t, b2, w3, b3, f_prevA, b_calcA, R, s);
  }

  int Rp = 17;
  float* prev = f_prevA;
  unsigned char* calcP = b_calcA;
  unsigned char* calcC = b_calcB;
  for (int li = 1; li <= 3; ++li){
    int R = 2 * Rp - 1;
    int s = 128 / (R - 1);
    unsigned int n = (unsigned int)R * (unsigned int)R * (unsigned int)R;
    int blocks = (int)((n + 255u) / 256u);
    const int T = (R + 7) / 8;
    const int tblocks = T * T * T;
    float* occ_out = (li == 3) ? out : ((prev == f_prevA) ? f_prevB : f_prevA);

    if (R == 33){
      // dense eval (low TLP suits pair core), then fused 3-step dilate (125 tiles)
      k_eval_mlp<<<blocks, 256, 0, stream>>>(w1, b1, f_w2t, b2, w3, b3, f_true, (unsigned char*)nullptr, R, s);
      k_resize_boundary<<<blocks, 256, 0, stream>>>(prev, f_true, calcP, f_occi, occ_out, b_b0, b_mism, calcC, R, Rp);
      k_dilate3_tiled<<<tblocks, 512, 0, stream>>>(b_b0, b_mism, calcC, f_true, occ_out, R, T);
    } else {
      // sparse: eval only on C = dilate^3(seed); 3 sparse dilate steps
      k_resize_b0<<<blocks, 256, 0, stream>>>(prev, calcP, f_occi, occ_out, b_b0, calcC,
                                              b_confA, b_confB, R, Rp);
      k_dil7_tiled<<<tblocks, 512, 0, stream>>>(b_b0, b_cand, u_bcnt, R, T);
      k_scan<<<1, 1024, 0, stream>>>(u_bcnt, (unsigned int)tblocks, u_cnt);
      k_scatter_tiled<<<tblocks, 512, 0, stream>>>(b_cand, u_bcnt, i_idx, R, T);
      k_eval_sparse<<<blocks, 256, 0, stream>>>(
          w1, b1, f_w2t, b2, w3, b3, i_idx, u_cnt, f_occi, f_true, b_mism, R, s, n);
      int sblocks = blocks < 4096 ? blocks : 4096;
      k_dilate_sparse<<<sblocks, 256, 0, stream>>>(i_idx, u_cnt, b_b0,    b_mism, calcC, b_confA, R, f_true, occ_out, n);
      k_dilate_sparse<<<sblocks, 256, 0, stream>>>(i_idx, u_cnt, b_confA, b_mism, calcC, b_confB, R, f_true, occ_out, n);
      k_dilate_sparse<<<sblocks, 256, 0, stream>>>(i_idx, u_cnt, b_confB, b_mism, calcC, b_confA, R, f_true, occ_out, n);
    }

    prev = occ_out;
    unsigned char* tmpc = calcP; calcP = calcC; calcC = tmpc;
    Rp = R;
  }
  (void)in_sizes; (void)n_in; (void)out_size;
}